// Round 3
// baseline (553.352 us; speedup 1.0000x reference)
//
#include <hip/hip_runtime.h>
#include <hip/hip_bf16.h>

#define N_NODES 50000
#define N_EDGES 1600000
#define IN_H 256
#define NHEAD 4
#define EDGE_H 64
#define N_ET 8

// ---- ws layout (word offsets), total 16,566,528 words = 66.3 MB ----
// counts   int[50000]     @ 0          (zeroed)
// cursor   int[50000]     @ 50000      (zeroed)
// hlmax    u32[4]         @ 100000     (zeroed; enc_f32-encoded maxima)
// hrmax    u32[4]         @ 100004
// hemax    u32[4]         @ 100008
// flag     int[1]         @ 100012
// hl       f32[200000]    @ 100064
// hr       f32[200000]    @ 300064
// offsets  int[50001]     @ 500064
// he       f32[32]        @ 550112
// Wt       bf16[32768]    @ 550144    (16384 words)
// rec      f32[12800000]  @ 566528    (32B/edge: p0..3, s, e, pad, pad)
// h        bf16[6400000]  @ 13366528  (3200000 words)

typedef __attribute__((ext_vector_type(8))) short bf16x8v;
typedef __attribute__((ext_vector_type(4))) float f32x4;

__device__ __forceinline__ float ldT(const float* p) { return *p; }
__device__ __forceinline__ float ldT(const __hip_bfloat16* p) { return __bfloat162float(*p); }
__device__ __forceinline__ void stT(float* p, float v) { *p = v; }
__device__ __forceinline__ void stT(__hip_bfloat16* p, float v) { *p = __float2bfloat16(v); }

__device__ __forceinline__ short f2bs(float f) {
    __hip_bfloat16 b = __float2bfloat16(f);
    return (short)__builtin_bit_cast(unsigned short, b);
}
__device__ __forceinline__ float bs2f(short s) {
    return __uint_as_float(((unsigned)(unsigned short)s) << 16);
}

__device__ __forceinline__ unsigned enc_f32(float f) {
    unsigned u = __float_as_uint(f);
    return (u & 0x80000000u) ? ~u : (u | 0x80000000u);
}
__device__ __forceinline__ float dec_f32(unsigned u) {
    return __uint_as_float((u & 0x80000000u) ? (u & 0x7fffffffu) : ~u);
}
__device__ __forceinline__ float lrelu(float v) { return v > 0.f ? v : 0.2f * v; }

// dtype detector: fp32 N(0,1) words have exp-field in [64,160]; bf16-packed don't.
__global__ void k_detect(const unsigned* __restrict__ xw, int* __restrict__ flag) {
    int lane = threadIdx.x;   // 64 threads
    int cnt = 0;
    for (int i = lane; i < 1024; i += 64) {
        unsigned e = (xw[i] >> 23) & 255u;
        if (e >= 64u && e <= 160u) cnt++;
    }
    for (int off = 32; off; off >>= 1) cnt += __shfl_xor(cnt, off);
    if (lane == 0) *flag = (cnt > 512) ? 1 : 0;   // 1 = fp32, 0 = bf16
}

// W[256][128] -> Wt[128][256] bf16 (B^T layout for MFMA, contiguous along K)
__global__ __launch_bounds__(256) void k_wt(const void* __restrict__ Wv,
        __hip_bfloat16* __restrict__ Wt, const int* __restrict__ flag) {
    bool f32 = (*flag != 0);
    for (int i = threadIdx.x; i < 128 * 256; i += 256) {
        int c = i >> 8, k = i & 255;
        float v = f32 ? ((const float*)Wv)[k * 128 + c]
                      : __bfloat162float(((const __hip_bfloat16*)Wv)[k * 128 + c]);
        Wt[i] = __float2bfloat16(v);
    }
}

__global__ __launch_bounds__(256) void k_count(
        const int* __restrict__ edge, int* __restrict__ counts) {
    int e = blockIdx.x * 256 + threadIdx.x;
    if (e < N_EDGES) atomicAdd(&counts[edge[N_EDGES + e]], 1);
}

// h = x @ W via mfma_f32_16x16x32_bf16.
// 4 waves/block = 2 row-groups x 2 col-halves. Wave: 16 rows x 64 cols
// (4 t-tiles), 12500 waves total (~8/SIMD). Epilogue computes hl/hr from
// the in-register h: each 16-col tile lies in one head; quarter-lane
// shfl reduce over cols; the two col-half waves own disjoint heads ->
// plain stores, no atomics, k_hlr eliminated.
template<typename T>
__device__ __forceinline__ void proj_body(const T* __restrict__ x,
        const __hip_bfloat16* __restrict__ Wt, __hip_bfloat16* __restrict__ h,
        float* __restrict__ hl, float* __restrict__ hr,
        const T* __restrict__ al, const T* __restrict__ ar) {
    int wid = threadIdx.x >> 6, lane = threadIdx.x & 63;
    int rg = blockIdx.x * 2 + (wid >> 1);
    if (rg >= 3125) return;                 // no barriers below: safe early-exit
    int toff = (wid & 1) * 4;               // col-half: t-tiles toff..toff+3
    int r0 = rg * 16;
    int r = lane & 15;
    int kb = (lane >> 4) * 8;
    const T* xrow = x + (size_t)(r0 + r) * IN_H;
    f32x4 z = {0.f, 0.f, 0.f, 0.f};
    f32x4 acc[4];
#pragma unroll
    for (int t = 0; t < 4; ++t) acc[t] = z;
#pragma unroll
    for (int kk = 0; kk < 8; ++kk) {
        int k0 = kk * 32 + kb;
        bf16x8v a;
        if constexpr (sizeof(T) == 4) {
            float4 lo = *(const float4*)(xrow + k0);
            float4 hi = *(const float4*)(xrow + k0 + 4);
            a[0] = f2bs(lo.x); a[1] = f2bs(lo.y); a[2] = f2bs(lo.z); a[3] = f2bs(lo.w);
            a[4] = f2bs(hi.x); a[5] = f2bs(hi.y); a[6] = f2bs(hi.z); a[7] = f2bs(hi.w);
        } else {
            a = *(const bf16x8v*)(xrow + k0);
        }
#pragma unroll
        for (int t = 0; t < 4; ++t) {
            bf16x8v b = *(const bf16x8v*)(Wt + ((toff + t) * 16 + r) * 256 + k0);
            acc[t] = __builtin_amdgcn_mfma_f32_16x16x32_bf16(a, b, acc[t], 0, 0, 0);
        }
    }
    // epilogue: store h, accumulate hl/hr partials
    float alc[4], arc[4];
#pragma unroll
    for (int t = 0; t < 4; ++t) {
        alc[t] = ldT(al + (toff + t) * 16 + r);
        arc[t] = ldT(ar + (toff + t) * 16 + r);
    }
    int ob = (lane >> 4) * 4;               // this quarter's row offset
    float pl[2][4] = {{0,0,0,0},{0,0,0,0}}, pr[2][4] = {{0,0,0,0},{0,0,0,0}};
#pragma unroll
    for (int t = 0; t < 4; ++t) {
        int col = (toff + t) * 16 + r;
#pragma unroll
        for (int g = 0; g < 4; ++g) {
            float v = acc[t][g];
            if (v != v) v = 0.f;            // reference: where(isnan(h), 0)
            h[(size_t)(r0 + ob + g) * 128 + col] = __float2bfloat16(v);
            pl[t >> 1][g] += alc[t] * v;
            pr[t >> 1][g] += arc[t] * v;
        }
    }
#pragma unroll
    for (int hh = 0; hh < 2; ++hh)
#pragma unroll
        for (int g = 0; g < 4; ++g) {
            float vl = pl[hh][g], vr = pr[hh][g];
#pragma unroll
            for (int off = 8; off; off >>= 1) {
                vl += __shfl_xor(vl, off);
                vr += __shfl_xor(vr, off);
            }
            if (r == 0) {
                int node = r0 + ob + g;
                hl[node * 4 + (toff >> 1) + hh] = vl;
                hr[node * 4 + (toff >> 1) + hh] = vr;
            }
        }
}

__global__ __launch_bounds__(256) void k_proj(const void* __restrict__ xv,
        const __hip_bfloat16* __restrict__ Wt, __hip_bfloat16* __restrict__ h,
        float* __restrict__ hl, float* __restrict__ hr,
        const void* __restrict__ al, const void* __restrict__ ar,
        const int* __restrict__ flag) {
    if (*flag) proj_body<float>((const float*)xv, Wt, h, hl, hr,
                                (const float*)al, (const float*)ar);
    else       proj_body<__hip_bfloat16>((const __hip_bfloat16*)xv, Wt, h, hl, hr,
                                         (const __hip_bfloat16*)al,
                                         (const __hip_bfloat16*)ar);
}

// block 0: edge-type projection he[ty][head] + hemax.
// blocks 1..128: per-head maxima of hl/hr (for the softmax shift bound).
template<typename T>
__device__ __forceinline__ void edge_proj_body(const T* __restrict__ emb,
        const T* __restrict__ We, const T* __restrict__ ae,
        float* __restrict__ h_e, unsigned* __restrict__ hemax) {
    int t = threadIdx.x;          // col 0..255, head = t>>6
    int lane = t & 63;
    float aev_ = ldT(ae + t);
    for (int ty = 0; ty < N_ET; ++ty) {
        float acc = 0.f;
        for (int k = 0; k < EDGE_H; ++k)
            acc += ldT(emb + ty * EDGE_H + k) * ldT(We + k * 256 + t);
        float v = aev_ * acc;
        for (int off = 32; off; off >>= 1) v += __shfl_xor(v, off);
        if (lane == 0) {
            h_e[ty * NHEAD + (t >> 6)] = v;
            atomicMax(&hemax[t >> 6], enc_f32(v));
        }
    }
}

__global__ __launch_bounds__(256) void k_aux(const void* __restrict__ emb,
        const void* __restrict__ We, const void* __restrict__ ae,
        float* __restrict__ h_e,
        const float* __restrict__ hl, const float* __restrict__ hr,
        unsigned* __restrict__ hlmax, unsigned* __restrict__ hrmax,
        unsigned* __restrict__ hemax, const int* __restrict__ flag) {
    if (blockIdx.x == 0) {
        if (*flag) edge_proj_body<float>((const float*)emb, (const float*)We,
                                         (const float*)ae, h_e, hemax);
        else       edge_proj_body<__hip_bfloat16>((const __hip_bfloat16*)emb,
                                                  (const __hip_bfloat16*)We,
                                                  (const __hip_bfloat16*)ae, h_e, hemax);
        return;
    }
    const float NEG = -3.4e38f;
    float4 ml = {NEG, NEG, NEG, NEG}, mr = {NEG, NEG, NEG, NEG};
    for (int n = (blockIdx.x - 1) * 256 + threadIdx.x; n < N_NODES; n += 128 * 256) {
        float4 a = *(const float4*)(hl + n * 4);
        float4 b = *(const float4*)(hr + n * 4);
        ml.x = fmaxf(ml.x, a.x); ml.y = fmaxf(ml.y, a.y);
        ml.z = fmaxf(ml.z, a.z); ml.w = fmaxf(ml.w, a.w);
        mr.x = fmaxf(mr.x, b.x); mr.y = fmaxf(mr.y, b.y);
        mr.z = fmaxf(mr.z, b.z); mr.w = fmaxf(mr.w, b.w);
    }
#pragma unroll
    for (int off = 32; off; off >>= 1) {
        ml.x = fmaxf(ml.x, __shfl_xor(ml.x, off));
        ml.y = fmaxf(ml.y, __shfl_xor(ml.y, off));
        ml.z = fmaxf(ml.z, __shfl_xor(ml.z, off));
        ml.w = fmaxf(ml.w, __shfl_xor(ml.w, off));
        mr.x = fmaxf(mr.x, __shfl_xor(mr.x, off));
        mr.y = fmaxf(mr.y, __shfl_xor(mr.y, off));
        mr.z = fmaxf(mr.z, __shfl_xor(mr.z, off));
        mr.w = fmaxf(mr.w, __shfl_xor(mr.w, off));
    }
    if ((threadIdx.x & 63) == 0) {
        atomicMax(&hlmax[0], enc_f32(ml.x)); atomicMax(&hlmax[1], enc_f32(ml.y));
        atomicMax(&hlmax[2], enc_f32(ml.z)); atomicMax(&hlmax[3], enc_f32(ml.w));
        atomicMax(&hrmax[0], enc_f32(mr.x)); atomicMax(&hrmax[1], enc_f32(mr.y));
        atomicMax(&hrmax[2], enc_f32(mr.z)); atomicMax(&hrmax[3], enc_f32(mr.w));
    }
}

__global__ __launch_bounds__(256) void k_scan(
        const int* __restrict__ counts, int* __restrict__ offsets) {
    __shared__ int psum[256];
    int t = threadIdx.x;
    const int CHUNK = 196;
    int start = t * CHUNK;
    int end = min(start + CHUNK, N_NODES);
    int s = 0;
    for (int i = start; i < end; ++i) s += counts[i];
    psum[t] = s;
    __syncthreads();
    for (int off = 1; off < 256; off <<= 1) {
        int v = (t >= off) ? psum[t - off] : 0;
        __syncthreads();
        psum[t] += v;
        __syncthreads();
    }
    int run = (t == 0) ? 0 : psum[t - 1];
    for (int i = start; i < end; ++i) { offsets[i] = run; run += counts[i]; }
    if (t == 255) offsets[N_NODES] = run;
}

// CSR build: per edge one 32B record {p0..p3, s, e, pad, pad}, where
// p_h = exp(score_h - M_h) with M_h = lrelu(max hl_h + max hr_h + max he_h)
// (monotone lrelu => valid upper bound; softmax is shift-invariant per head,
// so the result is mathematically identical to the reference's global max).
__global__ __launch_bounds__(256) void k_build(
        const int* __restrict__ edge, const int* __restrict__ offsets,
        int* __restrict__ cursor,
        const float* __restrict__ hl, const float* __restrict__ hr,
        const float* __restrict__ he,
        const unsigned* __restrict__ hlmax, const unsigned* __restrict__ hrmax,
        const unsigned* __restrict__ hemax,
        float* __restrict__ rec) {
    float M0 = lrelu(dec_f32(hlmax[0]) + dec_f32(hrmax[0]) + dec_f32(hemax[0]));
    float M1 = lrelu(dec_f32(hlmax[1]) + dec_f32(hrmax[1]) + dec_f32(hemax[1]));
    float M2 = lrelu(dec_f32(hlmax[2]) + dec_f32(hrmax[2]) + dec_f32(hemax[2]));
    float M3 = lrelu(dec_f32(hlmax[3]) + dec_f32(hrmax[3]) + dec_f32(hemax[3]));
    int e = blockIdx.x * 256 + threadIdx.x;   // 6250*256 == N_EDGES exactly
    int s = edge[e], t = edge[N_EDGES + e], ty = edge[2 * N_EDGES + e];
    int pos = offsets[t] + atomicAdd(&cursor[t], 1);
    float4 a = *(const float4*)(hl + s * 4);
    float4 b = *(const float4*)(hr + t * 4);
    float4 c = *(const float4*)(he + ty * 4);
    float4 p;
    p.x = __expf(lrelu(a.x + b.x + c.x) - M0);
    p.y = __expf(lrelu(a.y + b.y + c.y) - M1);
    p.z = __expf(lrelu(a.z + b.z + c.z) - M2);
    p.w = __expf(lrelu(a.w + b.w + c.w) - M3);
    float4 se;
    se.x = __int_as_float(s); se.y = __int_as_float(e); se.z = 0.f; se.w = 0.f;
    float* rp = rec + (size_t)pos * 8;
    *(float4*)rp = p;
    *(float4*)(rp + 4) = se;
}

// one wave per node. pass1: lane-parallel denom (pure sums, no exp).
// pass2: 4 edges/iter — quarter-wave owns an edge, 16 lanes own 8 dims each
// (16B h load), cross-quarter shfl reduce at end. Zero transcendentals.
template<typename OUTT>
__device__ __forceinline__ void agg_body(
        const float* __restrict__ rec, const int* __restrict__ offsets,
        const __hip_bfloat16* __restrict__ h, OUTT* __restrict__ out) {
    int node = (blockIdx.x << 2) + (threadIdx.x >> 6);
    if (node >= N_NODES) return;
    int lane = threadIdx.x & 63;
    int beg = offsets[node], end = offsets[node + 1];

    // pass 1: denominators
    float d0 = 0.f, d1 = 0.f, d2 = 0.f, d3 = 0.f;
    for (int j = beg + lane; j < end; j += 64) {
        float4 p = *(const float4*)(rec + (size_t)j * 8);
        d0 += p.x; d1 += p.y; d2 += p.z; d3 += p.w;
    }
#pragma unroll
    for (int off = 32; off; off >>= 1) {
        d0 += __shfl_xor(d0, off); d1 += __shfl_xor(d1, off);
        d2 += __shfl_xor(d2, off); d3 += __shfl_xor(d3, off);
    }
    float inv0 = 1.f / (d0 + 1e-16f), inv1 = 1.f / (d1 + 1e-16f);
    float inv2 = 1.f / (d2 + 1e-16f), inv3 = 1.f / (d3 + 1e-16f);

    int sub = lane >> 4;          // edge slot within group of 4
    int l16 = lane & 15;          // dim group: flat dims l16*8 .. +8
    int hd  = l16 >> 2;           // head of my dims
    float invd = hd == 0 ? inv0 : hd == 1 ? inv1 : hd == 2 ? inv2 : inv3;
    float inva = l16 == 0 ? inv0 : l16 == 1 ? inv1 : l16 == 2 ? inv2 : inv3;
    OUTT* attn_out = out + (size_t)N_NODES * 128;

    float acc[8] = {0.f, 0.f, 0.f, 0.f, 0.f, 0.f, 0.f, 0.f};
    for (int jg = beg; jg < end; jg += 4) {
        int j = jg + sub;
        bool valid = j < end;
        int jc = valid ? j : end - 1;
        const float* rp = rec + (size_t)jc * 8;
        float4 p = *(const float4*)rp;
        int2 se = *(const int2*)(rp + 4);
        int s = se.x;
        if (valid && l16 < 4) {    // attn output: lanes 0..3 of each quarter
            float ph = l16 == 0 ? p.x : l16 == 1 ? p.y : l16 == 2 ? p.z : p.w;
            stT(&attn_out[(size_t)se.y * 4 + l16], ph * inva);
        }
        float phd = hd == 0 ? p.x : hd == 1 ? p.y : hd == 2 ? p.z : p.w;
        float w = valid ? phd * invd : 0.f;
        bf16x8v hv = *(const bf16x8v*)(h + (size_t)s * 128 + l16 * 8);
#pragma unroll
        for (int i = 0; i < 8; ++i) acc[i] += bs2f(hv[i]) * w;
    }
#pragma unroll
    for (int i = 0; i < 8; ++i) {
        acc[i] += __shfl_xor(acc[i], 16);
        acc[i] += __shfl_xor(acc[i], 32);
    }
    if (sub == 0) {
#pragma unroll
        for (int i = 0; i < 8; ++i)
            stT(&out[(size_t)node * 128 + l16 * 8 + i], acc[i]);
    }
}

__global__ __launch_bounds__(256) void k_agg(
        const float* __restrict__ rec, const int* __restrict__ offsets,
        const __hip_bfloat16* __restrict__ h,
        void* __restrict__ outv, const int* __restrict__ flag) {
    if (*flag) agg_body<float>(rec, offsets, h, (float*)outv);
    else       agg_body<__hip_bfloat16>(rec, offsets, h, (__hip_bfloat16*)outv);
}

extern "C" void kernel_launch(void* const* d_in, const int* in_sizes, int n_in,
                              void* d_out, int out_size, void* d_ws, size_t ws_size,
                              hipStream_t stream) {
    const int* edge = (const int*)d_in[0];
    const void* x   = d_in[1];
    const void* emb = d_in[2];
    const void* W   = d_in[3];
    const void* We  = d_in[4];
    const void* al  = d_in[5];
    const void* ar  = d_in[6];
    const void* ae  = d_in[7];

    float* ws = (float*)d_ws;
    int* counts     = (int*)ws;                        // 50000
    int* cursor     = counts + 50000;                  // 50000
    unsigned* hlmax = (unsigned*)(counts + 100000);    // 4
    unsigned* hrmax = hlmax + 4;                       // 4
    unsigned* hemax = hlmax + 8;                       // 4
    int* flag       = counts + 100012;                 // 1
    float* hl       = ws + 100064;                     // 200000
    float* hr       = ws + 300064;                     // 200000
    int* offsets    = (int*)ws + 500064;               // 50001
    float* he       = ws + 550112;                     // 32
    __hip_bfloat16* Wt = (__hip_bfloat16*)(ws + 550144);   // 32768 bf16
    float* rec      = ws + 566528;                     // 12,800,000 (32B-aligned)
    __hip_bfloat16* h = (__hip_bfloat16*)(ws + 13366528);  // 6,400,000 bf16
    // total 16,566,528 words = 66.3 MB

    hipMemsetAsync(ws, 0, (size_t)100064 * 4, stream); // counts+cursor+maxima+flag

    k_detect<<<1, 64, 0, stream>>>((const unsigned*)x, flag);
    k_wt<<<1, 256, 0, stream>>>(W, Wt, flag);
    k_count<<<6250, 256, 0, stream>>>(edge, counts);
    k_proj<<<1563, 256, 0, stream>>>(x, Wt, h, hl, hr, al, ar, flag);
    k_aux<<<129, 256, 0, stream>>>(emb, We, ae, he, hl, hr, hlmax, hrmax, hemax, flag);
    k_scan<<<1, 256, 0, stream>>>(counts, offsets);
    k_build<<<6250, 256, 0, stream>>>(edge, offsets, cursor, hl, hr, he,
                                      hlmax, hrmax, hemax, rec);
    k_agg<<<12500, 256, 0, stream>>>(rec, offsets, h, d_out, flag);
}